// Round 1
// baseline (119.724 us; speedup 1.0000x reference)
//
#include <hip/hip_runtime.h>

#define RATE 0.001f

// Fused layer: vj = relu(vi @ w.T + bias); then
// out[b,o] = vj[b,o] + scale * ( sum_i a_i * (sum_h relu(a_i*p_h + w_oi*q_h + k_bh) * c2w_h)
//                                + c2b * sum_i a_i )
// where k_bh = vj[b,o]*r_h + c1b_h, scale = RATE / batch_num.
// One block per output neuron o; 256 threads stride over I; all 8 batch rows per block.
template<int I>
__global__ __launch_bounds__(256) void hebb_layer(
    const float* __restrict__ vi,    // (8, I)
    const float* __restrict__ w,     // (O, I)
    const float* __restrict__ bias,  // (O,)
    const float* __restrict__ c1w,   // (8, 3) row-major: p,q,r
    const float* __restrict__ c1b,   // (8,)
    const float* __restrict__ c2w,   // (8,)
    const float* __restrict__ c2b_p, // scalar
    const int*   __restrict__ bn_p,  // scalar batch_num
    float* __restrict__ out,         // (8, O)
    int O)
{
    const int o    = blockIdx.x;
    const int tid  = threadIdx.x;
    const int lane = tid & 63;
    const int wid  = tid >> 6;

    __shared__ float red[4][16];     // [wave][b: 0..7 = dot, 8..15 = rowsum]
    __shared__ float s_vj[8];
    __shared__ float s_S[8];

    // uniform constants (compiler should scalarize these loads)
    float p[8], q[8], r[8], cb[8], c2[8];
#pragma unroll
    for (int h = 0; h < 8; ++h) {
        p[h]  = c1w[h * 3 + 0];
        q[h]  = c1w[h * 3 + 1];
        r[h]  = c1w[h * 3 + 2];
        cb[h] = c1b[h];
        c2[h] = c2w[h];
    }
    const float c2b   = *c2b_p;
    const float scale = RATE / (float)(*bn_p);
    const float bo    = bias[o];
    const float* __restrict__ wrow = w + (size_t)o * I;

    // ---------------- pass 1: dot products + row sums ----------------
    float dot[8], ss[8];
#pragma unroll
    for (int b = 0; b < 8; ++b) { dot[b] = 0.f; ss[b] = 0.f; }

    for (int i = tid; i < I; i += 256) {
        const float wv = wrow[i];
#pragma unroll
        for (int b = 0; b < 8; ++b) {
            const float a = vi[b * I + i];
            dot[b] = fmaf(a, wv, dot[b]);
            ss[b] += a;
        }
    }
#pragma unroll
    for (int b = 0; b < 8; ++b) {
#pragma unroll
        for (int off = 32; off; off >>= 1) {
            dot[b] += __shfl_down(dot[b], off, 64);
            ss[b]  += __shfl_down(ss[b],  off, 64);
        }
    }
    if (lane == 0) {
#pragma unroll
        for (int b = 0; b < 8; ++b) { red[wid][b] = dot[b]; red[wid][8 + b] = ss[b]; }
    }
    __syncthreads();
    if (tid < 8) {
        const float d = red[0][tid] + red[1][tid] + red[2][tid] + red[3][tid];
        const float s = red[0][8 + tid] + red[1][8 + tid] + red[2][8 + tid] + red[3][8 + tid];
        s_vj[tid] = fmaxf(d + bo, 0.f);
        s_S[tid]  = s;
    }
    __syncthreads();

    // k[b][h] = vj_b * r_h + c1b_h  (registers, fully unrolled)
    float k[8][8];
#pragma unroll
    for (int b = 0; b < 8; ++b) {
        const float v = s_vj[b];
#pragma unroll
        for (int h = 0; h < 8; ++h) k[b][h] = fmaf(v, r[h], cb[h]);
    }

    // ---------------- pass 2: meta-MLP accumulation ----------------
    float acc[8];
#pragma unroll
    for (int b = 0; b < 8; ++b) acc[b] = 0.f;

    for (int i = tid; i < I; i += 256) {
        const float wv = wrow[i];
        float m[8];
#pragma unroll
        for (int h = 0; h < 8; ++h) m[h] = wv * q[h];
        float a[8];
#pragma unroll
        for (int b = 0; b < 8; ++b) a[b] = vi[b * I + i];
#pragma unroll
        for (int b = 0; b < 8; ++b) {
            float t = 0.f;
#pragma unroll
            for (int h = 0; h < 8; ++h) {
                const float u = fmaxf(fmaf(a[b], p[h], m[h] + k[b][h]), 0.f);
                t = fmaf(u, c2[h], t);
            }
            acc[b] = fmaf(a[b], t, acc[b]);
        }
    }

#pragma unroll
    for (int b = 0; b < 8; ++b) {
#pragma unroll
        for (int off = 32; off; off >>= 1) acc[b] += __shfl_down(acc[b], off, 64);
    }
    __syncthreads();   // red[] reuse: make sure pass-1 consumers are done
    if (lane == 0) {
#pragma unroll
        for (int b = 0; b < 8; ++b) red[wid][b] = acc[b];
    }
    __syncthreads();
    if (tid < 8) {
        const float rsum = red[0][tid] + red[1][tid] + red[2][tid] + red[3][tid];
        out[tid * O + o] = s_vj[tid] + scale * (rsum + c2b * s_S[tid]);
    }
}

extern "C" void kernel_launch(void* const* d_in, const int* in_sizes, int n_in,
                              void* d_out, int out_size, void* d_ws, size_t ws_size,
                              hipStream_t stream) {
    const float* x   = (const float*)d_in[0];   // (8, 1024)
    const float* w1  = (const float*)d_in[1];   // (2048, 1024)
    const float* b1  = (const float*)d_in[2];   // (2048,)
    const float* w2  = (const float*)d_in[3];   // (512, 2048)
    const float* b2  = (const float*)d_in[4];   // (512,)
    const float* c1w = (const float*)d_in[5];   // (8, 3)
    const float* c1b = (const float*)d_in[6];   // (8,)
    const float* c2w = (const float*)d_in[7];   // (8,)
    const float* c2b = (const float*)d_in[8];   // ()
    const int*   bn  = (const int*)d_in[9];     // scalar

    float* out = (float*)d_out;                 // (8, 512) fp32
    float* mid = (float*)d_ws;                  // (8, 2048) fp32 = 64 KB

    hebb_layer<1024><<<2048, 256, 0, stream>>>(x,   w1, b1, c1w, c1b, c2w, c2b, bn, mid, 2048);
    hebb_layer<2048><<<512,  256, 0, stream>>>(mid, w2, b2, c1w, c1b, c2w, c2b, bn, out, 512);
}

// Round 2
// 102.869 us; speedup vs baseline: 1.1638x; 1.1638x over previous
//
#include <hip/hip_runtime.h>

#define RATE 0.001f

typedef float f2 __attribute__((ext_vector_type(2)));
typedef float f4 __attribute__((ext_vector_type(4)));

static __device__ __forceinline__ f2 splat2(float v) { f2 r; r.x = v; r.y = v; return r; }

// out[b,o] = vj + scale*( sum_i a_i * (sum_h relu(a_i*p_h + w_oi*q_h + vj*r_h + c1b_h)*c2w_h)
//                         + c2b * sum_i a_i ),  vj = relu(dot(a_b, w_o) + bias_o)
//
// Grid: one block per output neuron o. Block = 256 = 4 waves.
// Wave w owns batch rows {2w, 2w+1} across the FULL I range -> all reductions are
// wave-local (butterfly shuffles), no LDS, no __syncthreads.
// h-dimension (8) packed into 4 x float2 -> v_pk_fma_f32 / v_pk_max_f32.
template<int I>
__global__ __launch_bounds__(256) void hebb_layer(
    const float* __restrict__ vi,    // (8, I)
    const float* __restrict__ w,     // (O, I)
    const float* __restrict__ bias,  // (O,)
    const float* __restrict__ c1w,   // (8, 3): p,q,r
    const float* __restrict__ c1b,   // (8,)
    const float* __restrict__ c2w,   // (8,)
    const float* __restrict__ c2b_p, // scalar
    const int*   __restrict__ bn_p,  // scalar batch_num
    float* __restrict__ out,         // (8, O)
    int O)
{
    const int o    = blockIdx.x;
    const int tid  = threadIdx.x;
    const int lane = tid & 63;
    const int wid  = tid >> 6;     // wave 0..3 -> batch pair {2*wid, 2*wid+1}
    const int b0   = wid * 2;

    // packed per-h constants (uniform scalar loads -> SGPRs)
    f2 p2[4], q2[4], r2[4], cb2[4], c22[4];
#pragma unroll
    for (int j = 0; j < 4; ++j) {
        p2[j].x  = c1w[(2*j)*3 + 0];  p2[j].y  = c1w[(2*j+1)*3 + 0];
        q2[j].x  = c1w[(2*j)*3 + 1];  q2[j].y  = c1w[(2*j+1)*3 + 1];
        r2[j].x  = c1w[(2*j)*3 + 2];  r2[j].y  = c1w[(2*j+1)*3 + 2];
        cb2[j].x = c1b[2*j];          cb2[j].y = c1b[2*j+1];
        c22[j].x = c2w[2*j];          c22[j].y = c2w[2*j+1];
    }
    const float c2b   = *c2b_p;
    const float scale = RATE / (float)(*bn_p);
    const float bo    = bias[o];

    const float* __restrict__ wrow  = w  + (size_t)o  * I;
    const float* __restrict__ arow0 = vi + (size_t)b0 * I;
    const float* __restrict__ arow1 = arow0 + I;

    constexpr int ITERS = I / 256;   // 64 lanes x 4 floats per iter

    // ---- pass 1: dot(a_b, w_o) and rowsum(a_b) for the wave's two b's ----
    float dot0 = 0.f, dot1 = 0.f, ss0 = 0.f, ss1 = 0.f;
    for (int it = 0; it < ITERS; ++it) {
        const int base = it * 256 + lane * 4;
        const f4 wv = *(const f4*)(wrow  + base);
        const f4 a0 = *(const f4*)(arow0 + base);
        const f4 a1 = *(const f4*)(arow1 + base);
#pragma unroll
        for (int e = 0; e < 4; ++e) {
            dot0 = fmaf(a0[e], wv[e], dot0);
            dot1 = fmaf(a1[e], wv[e], dot1);
            ss0 += a0[e];
            ss1 += a1[e];
        }
    }
#pragma unroll
    for (int off = 1; off < 64; off <<= 1) {
        dot0 += __shfl_xor(dot0, off, 64);
        dot1 += __shfl_xor(dot1, off, 64);
        ss0  += __shfl_xor(ss0,  off, 64);
        ss1  += __shfl_xor(ss1,  off, 64);
    }
    const float vj0 = fmaxf(dot0 + bo, 0.f);
    const float vj1 = fmaxf(dot1 + bo, 0.f);

    // k[b][h] = vj_b * r_h + c1b_h  (packed, 16 VGPRs total)
    f2 k20[4], k21[4];
#pragma unroll
    for (int j = 0; j < 4; ++j) {
        k20[j] = splat2(vj0) * r2[j] + cb2[j];
        k21[j] = splat2(vj1) * r2[j] + cb2[j];
    }

    // ---- pass 2: meta-MLP accumulation ----
    f2 acc0 = splat2(0.f), acc1 = splat2(0.f);
    for (int it = 0; it < ITERS; ++it) {
        const int base = it * 256 + lane * 4;
        const f4 wv4 = *(const f4*)(wrow  + base);
        const f4 a04 = *(const f4*)(arow0 + base);
        const f4 a14 = *(const f4*)(arow1 + base);
#pragma unroll
        for (int e = 0; e < 4; ++e) {
            const f2 wvE = splat2(wv4[e]);
            const f2 a0E = splat2(a04[e]);
            const f2 a1E = splat2(a14[e]);
            f2 t0 = splat2(0.f), t1 = splat2(0.f);
#pragma unroll
            for (int j = 0; j < 4; ++j) {
                f2 z0 = wvE * q2[j] + k20[j];
                z0 = a0E * p2[j] + z0;
                const f2 u0 = __builtin_elementwise_max(z0, splat2(0.f));
                t0 = u0 * c22[j] + t0;
                f2 z1 = wvE * q2[j] + k21[j];
                z1 = a1E * p2[j] + z1;
                const f2 u1 = __builtin_elementwise_max(z1, splat2(0.f));
                t1 = u1 * c22[j] + t1;
            }
            acc0 = a0E * t0 + acc0;
            acc1 = a1E * t1 + acc1;
        }
    }
    float r0 = acc0.x + acc0.y;
    float r1 = acc1.x + acc1.y;
#pragma unroll
    for (int off = 1; off < 64; off <<= 1) {
        r0 += __shfl_xor(r0, off, 64);
        r1 += __shfl_xor(r1, off, 64);
    }

    if (lane == 0) {
        out[(size_t)(b0    ) * O + o] = vj0 + scale * (r0 + c2b * ss0);
        out[(size_t)(b0 + 1) * O + o] = vj1 + scale * (r1 + c2b * ss1);
    }
}

extern "C" void kernel_launch(void* const* d_in, const int* in_sizes, int n_in,
                              void* d_out, int out_size, void* d_ws, size_t ws_size,
                              hipStream_t stream) {
    const float* x   = (const float*)d_in[0];   // (8, 1024)
    const float* w1  = (const float*)d_in[1];   // (2048, 1024)
    const float* b1  = (const float*)d_in[2];   // (2048,)
    const float* w2  = (const float*)d_in[3];   // (512, 2048)
    const float* b2  = (const float*)d_in[4];   // (512,)
    const float* c1w = (const float*)d_in[5];   // (8, 3)
    const float* c1b = (const float*)d_in[6];   // (8,)
    const float* c2w = (const float*)d_in[7];   // (8,)
    const float* c2b = (const float*)d_in[8];   // ()
    const int*   bn  = (const int*)d_in[9];     // scalar

    float* out = (float*)d_out;                 // (8, 512) fp32
    float* mid = (float*)d_ws;                  // (8, 2048) fp32 = 64 KB

    hebb_layer<1024><<<2048, 256, 0, stream>>>(x,   w1, b1, c1w, c1b, c2w, c2b, bn, mid, 2048);
    hebb_layer<2048><<<512,  256, 0, stream>>>(mid, w2, b2, c1w, c1b, c2w, c2b, bn, out, 512);
}